// Round 2
// baseline (1697.633 us; speedup 1.0000x reference)
//
#include <hip/hip_runtime.h>
#include <math.h>

#define N_NODES 50000
#define N_EDGES 1600000
#define N_GRAPH 500

// ---------- helpers ----------
__device__ __forceinline__ unsigned f2u_ord(float f) {
    unsigned b = __float_as_uint(f);
    return (b & 0x80000000u) ? ~b : (b | 0x80000000u);
}
__device__ __forceinline__ float u2f_ord(unsigned u) {
    return __uint_as_float((u & 0x80000000u) ? (u ^ 0x80000000u) : ~u);
}

// ---------- CSR build ----------
__global__ void hist_kernel(const int* __restrict__ dst, int* __restrict__ deg, int E) {
    int e = blockIdx.x * blockDim.x + threadIdx.x;
    if (e < E) atomicAdd(&deg[dst[e]], 1);
}

__global__ void scan_kernel(const int* __restrict__ deg, int* __restrict__ rowptr,
                            int* __restrict__ cursor, int N) {
    __shared__ int part[1024];
    int t = threadIdx.x;
    int chunk = (N + 1023) / 1024;
    int lo = t * chunk;
    int hi = min(lo + chunk, N);
    int s = 0;
    for (int i = lo; i < hi; i++) s += deg[i];
    part[t] = s;
    __syncthreads();
    for (int off = 1; off < 1024; off <<= 1) {
        int add = (t >= off) ? part[t - off] : 0;
        __syncthreads();
        part[t] += add;
        __syncthreads();
    }
    int run = (t == 0) ? 0 : part[t - 1];
    for (int i = lo; i < hi; i++) {
        rowptr[i] = run;
        cursor[i] = run;
        run += deg[i];
    }
    if (t == 1023) rowptr[N] = part[1023];
}

__global__ void fill_kernel(const int* __restrict__ src, const int* __restrict__ dst,
                            int* __restrict__ cursor, int* __restrict__ csr_src, int E) {
    int e = blockIdx.x * blockDim.x + threadIdx.x;
    if (e < E) {
        int d = dst[e];
        int pos = atomicAdd(&cursor[d], 1);
        csr_src[pos] = src[e];
    }
}

// ---------- gemm0: y0 = x @ W1_0  (N x 128 -> N x 64) ----------
__global__ __launch_bounds__(512) void gemm0_kernel(const float* __restrict__ x,
                                                    const float* __restrict__ W1,
                                                    float* __restrict__ y0,
                                                    int N, int totalWaves) {
    __shared__ float sW1[128 * 64];
    int tid = threadIdx.x;
    for (int i = tid; i < 128 * 64; i += 512) sW1[i] = W1[i];
    __syncthreads();
    int lane = tid & 63;
    int wid = (blockIdx.x * 512 + tid) >> 6;
    for (int row = wid; row < N; row += totalWaves) {
        float xa = x[(size_t)row * 128 + lane];
        float xb = x[(size_t)row * 128 + 64 + lane];
        float acc = 0.f;
#pragma unroll
        for (int k = 0; k < 64; k++) acc = fmaf(__shfl(xa, k), sW1[k * 64 + lane], acc);
#pragma unroll
        for (int k = 0; k < 64; k++) acc = fmaf(__shfl(xb, k), sW1[(64 + k) * 64 + lane], acc);
        y0[(size_t)row * 64 + lane] = acc;
    }
}

// ---------- fused per-layer kernel ----------
// in:  y = h_layer @ W1_layer  (N x 64)
// u   = y[node] + sum_{src} y[src] + b1        (linearity of segment_sum)
// t   = relu(u);  h = t @ W2 + b2; relu if LAYER<2
// score[node] (=/+)= h . Wm[LAYER*64..+64]
// ynext = h @ W1_{LAYER+1}                     (LAYER<2)
template <int LAYER>
__global__ __launch_bounds__(512) void layer_kernel(const float* __restrict__ y,
                                                    const float* __restrict__ b1,
                                                    const float* __restrict__ W2,
                                                    const float* __restrict__ b2,
                                                    const float* __restrict__ W1n,
                                                    const float* __restrict__ Wm,
                                                    const int* __restrict__ rowptr,
                                                    const int* __restrict__ csr_src,
                                                    float* __restrict__ ynext,
                                                    float* __restrict__ score,
                                                    int N, int totalWaves) {
    __shared__ float sW2[64 * 64];
    __shared__ float sW1n[(LAYER < 2) ? 64 * 64 : 1];
    __shared__ float sb1[64], sb2[64], sWm[64];
    int tid = threadIdx.x;
    for (int i = tid; i < 64 * 64; i += 512) sW2[i] = W2[i];
    if (LAYER < 2)
        for (int i = tid; i < 64 * 64; i += 512) sW1n[i] = W1n[i];
    if (tid < 64) {
        sb1[tid] = b1[tid];
        sb2[tid] = b2[tid];
        sWm[tid] = Wm[LAYER * 64 + tid];
    }
    __syncthreads();
    int lane = tid & 63;
    int wid = (blockIdx.x * 512 + tid) >> 6;

    for (int node = wid; node < N; node += totalWaves) {
        int start = rowptr[node];
        int end = rowptr[node + 1];
        float u = y[(size_t)node * 64 + lane];
        for (int j = start; j < end; j++) {
            int s = csr_src[j];
            u += y[(size_t)s * 64 + lane];
        }
        float t = fmaxf(u + sb1[lane], 0.f);

        float h = sb2[lane];
#pragma unroll
        for (int k = 0; k < 64; k++) h = fmaf(__shfl(t, k), sW2[k * 64 + lane], h);
        if (LAYER < 2) h = fmaxf(h, 0.f);

        float p = h * sWm[lane];
#pragma unroll
        for (int o = 32; o >= 1; o >>= 1) p += __shfl_xor(p, o);
        if (lane == 0) {
            if (LAYER == 0) score[node] = p;
            else score[node] += p;
        }

        if (LAYER < 2) {
            float yn = 0.f;
#pragma unroll
            for (int k = 0; k < 64; k++) yn = fmaf(__shfl(h, k), sW1n[k * 64 + lane], yn);
            ynext[(size_t)node * 64 + lane] = yn;
        }
    }
}

// ---------- edge softmax + new_score, per dst node ----------
__global__ __launch_bounds__(256) void edge_softmax_kernel(const float* __restrict__ score,
                                                           const int* __restrict__ rowptr,
                                                           const int* __restrict__ csr_src,
                                                           const float* __restrict__ bm,
                                                           float* __restrict__ nsf, int N) {
    int wid = (blockIdx.x * blockDim.x + threadIdx.x) >> 6;
    int lane = threadIdx.x & 63;
    if (wid >= N) return;
    float b = bm[0];
    float sd = score[wid] + b;
    int start = rowptr[wid];
    int end = rowptr[wid + 1];
    float m = -INFINITY;
    for (int j = start + lane; j < end; j += 64) {
        float ss = score[csr_src[j]] + b;
        m = fmaxf(m, ss * sd);
    }
#pragma unroll
    for (int o = 32; o >= 1; o >>= 1) m = fmaxf(m, __shfl_xor(m, o));
    float se = 0.f, swe = 0.f;
    if (m > -INFINITY) {
        for (int j = start + lane; j < end; j += 64) {
            float ss = score[csr_src[j]] + b;
            float e = expf(ss * sd - m);
            se += e;
            swe += ss * e;
        }
#pragma unroll
        for (int o = 32; o >= 1; o >>= 1) {
            se += __shfl_xor(se, o);
            swe += __shfl_xor(swe, o);
        }
    }
    float ns = (se > 0.f) ? (swe / se) : 0.f;
    if (lane == 0) nsf[wid] = sd + ns;
}

// ---------- graph-segment softmax ----------
__global__ void gmax_kernel(const float* __restrict__ nsf, const int* __restrict__ batch,
                            unsigned* __restrict__ gmaxu, int N) {
    int i = blockIdx.x * blockDim.x + threadIdx.x;
    if (i < N) atomicMax(&gmaxu[batch[i]], f2u_ord(nsf[i]));
}
__global__ void gexp_kernel(const float* __restrict__ nsf, const int* __restrict__ batch,
                            const unsigned* __restrict__ gmaxu, float* __restrict__ gsum,
                            float* __restrict__ out, int N) {
    int i = blockIdx.x * blockDim.x + threadIdx.x;
    if (i < N) {
        int b = batch[i];
        float m = u2f_ord(gmaxu[b]);
        float e = expf(nsf[i] - m);
        out[i] = e;
        atomicAdd(&gsum[b], e);
    }
}
__global__ void gdiv_kernel(const int* __restrict__ batch, const float* __restrict__ gsum,
                            float* __restrict__ out, int N) {
    int i = blockIdx.x * blockDim.x + threadIdx.x;
    if (i < N) out[i] /= gsum[batch[i]];
}

extern "C" void kernel_launch(void* const* d_in, const int* in_sizes, int n_in,
                              void* d_out, int out_size, void* d_ws, size_t ws_size,
                              hipStream_t stream) {
    const int N = N_NODES, E = N_EDGES, G = N_GRAPH;

    const float* x = (const float*)d_in[0];
    const int* ei = (const int*)d_in[1];
    const int* batch = (const int*)d_in[2];
    const float* W1a[3] = {(const float*)d_in[3], (const float*)d_in[7], (const float*)d_in[11]};
    const float* b1a[3] = {(const float*)d_in[4], (const float*)d_in[8], (const float*)d_in[12]};
    const float* W2a[3] = {(const float*)d_in[5], (const float*)d_in[9], (const float*)d_in[13]};
    const float* b2a[3] = {(const float*)d_in[6], (const float*)d_in[10], (const float*)d_in[14]};
    const float* Wm = (const float*)d_in[15];
    const float* bm = (const float*)d_in[16];
    float* out = (float*)d_out;

    const int* srcp = ei;
    const int* dstp = ei + E;

    // workspace layout
    float* yA = (float*)d_ws;                   // N*64
    float* yB = yA + (size_t)N * 64;            // N*64
    float* score = yB + (size_t)N * 64;         // N
    float* nsf = score + N;                     // N
    float* gsum = nsf + N;                      // G
    unsigned* gmaxu = (unsigned*)(gsum + G);    // G
    int* deg = (int*)(gmaxu + G);               // N
    int* rowptr = deg + N;                      // N+1
    int* cursor = rowptr + N + 1;               // N
    int* csr_src = cursor + N;                  // E

    hipMemsetAsync(deg, 0, sizeof(int) * N, stream);
    hipMemsetAsync(gmaxu, 0, sizeof(unsigned) * G, stream);
    hipMemsetAsync(gsum, 0, sizeof(float) * G, stream);

    hist_kernel<<<E / 256, 256, 0, stream>>>(dstp, deg, E);
    scan_kernel<<<1, 1024, 0, stream>>>(deg, rowptr, cursor, N);
    fill_kernel<<<E / 256, 256, 0, stream>>>(srcp, dstp, cursor, csr_src, E);

    // y0 = x @ W1_0
    const int gemmWaves = 256 * 8;
    gemm0_kernel<<<256, 512, 0, stream>>>(x, W1a[0], yA, N, gemmWaves);

    const int layerBlocks = 1024;
    const int layerWaves = layerBlocks * 8;
    layer_kernel<0><<<layerBlocks, 512, 0, stream>>>(yA, b1a[0], W2a[0], b2a[0], W1a[1], Wm,
                                                     rowptr, csr_src, yB, score, N, layerWaves);
    layer_kernel<1><<<layerBlocks, 512, 0, stream>>>(yB, b1a[1], W2a[1], b2a[1], W1a[2], Wm,
                                                     rowptr, csr_src, yA, score, N, layerWaves);
    layer_kernel<2><<<layerBlocks, 512, 0, stream>>>(yA, b1a[2], W2a[2], b2a[2], nullptr, Wm,
                                                     rowptr, csr_src, nullptr, score, N, layerWaves);

    edge_softmax_kernel<<<N / 4, 256, 0, stream>>>(score, rowptr, csr_src, bm, nsf, N);

    int nb = (N + 255) / 256;
    gmax_kernel<<<nb, 256, 0, stream>>>(nsf, batch, gmaxu, N);
    gexp_kernel<<<nb, 256, 0, stream>>>(nsf, batch, gmaxu, gsum, out, N);
    gdiv_kernel<<<nb, 256, 0, stream>>>(batch, gsum, out, N);
}

// Round 3
// 672.020 us; speedup vs baseline: 2.5262x; 2.5262x over previous
//
#include <hip/hip_runtime.h>
#include <math.h>

#define N_NODES 50000
#define N_EDGES 1600000
#define N_GRAPH 500

// ---------- helpers ----------
__device__ __forceinline__ unsigned f2u_ord(float f) {
    unsigned b = __float_as_uint(f);
    return (b & 0x80000000u) ? ~b : (b | 0x80000000u);
}
__device__ __forceinline__ float u2f_ord(unsigned u) {
    return __uint_as_float((u & 0x80000000u) ? (u ^ 0x80000000u) : ~u);
}
// wave-broadcast of lane k's value (k compile-time constant in unrolled loops)
__device__ __forceinline__ float rl(float v, int k) {
    return __int_as_float(__builtin_amdgcn_readlane(__float_as_int(v), k));
}

// ---------- CSR build ----------
__global__ void hist_kernel(const int* __restrict__ dst, int* __restrict__ deg, int E) {
    int e = blockIdx.x * blockDim.x + threadIdx.x;
    if (e < E) atomicAdd(&deg[dst[e]], 1);
}

__global__ void scan_kernel(const int* __restrict__ deg, int* __restrict__ rowptr,
                            int* __restrict__ cursor, int N) {
    __shared__ int part[1024];
    int t = threadIdx.x;
    int chunk = (N + 1023) / 1024;
    int lo = t * chunk;
    int hi = min(lo + chunk, N);
    int s = 0;
    for (int i = lo; i < hi; i++) s += deg[i];
    part[t] = s;
    __syncthreads();
    for (int off = 1; off < 1024; off <<= 1) {
        int add = (t >= off) ? part[t - off] : 0;
        __syncthreads();
        part[t] += add;
        __syncthreads();
    }
    int run = (t == 0) ? 0 : part[t - 1];
    for (int i = lo; i < hi; i++) {
        rowptr[i] = run;
        cursor[i] = run;
        run += deg[i];
    }
    if (t == 1023) rowptr[N] = part[1023];
}

__global__ void fill_kernel(const int* __restrict__ src, const int* __restrict__ dst,
                            int* __restrict__ cursor, int* __restrict__ csr_src, int E) {
    int e = blockIdx.x * blockDim.x + threadIdx.x;
    if (e < E) {
        int d = dst[e];
        int pos = atomicAdd(&cursor[d], 1);
        csr_src[pos] = src[e];
    }
}

// ---------- aggregation on 64-wide y: u[d] = y[d] + sum_{e: dst=d} y[src_e]
// One wave per node; 8 independent row-loads in flight per iteration.
__global__ __launch_bounds__(256) void agg_kernel(const float* __restrict__ y,
                                                  const int* __restrict__ rowptr,
                                                  const int* __restrict__ csr_src,
                                                  float* __restrict__ u, int N) {
    int wid = (blockIdx.x * 256 + threadIdx.x) >> 6;
    int lane = threadIdx.x & 63;
    if (wid >= N) return;
    const float* yl = y + lane;
    int start = rowptr[wid];
    int end = rowptr[wid + 1];
    float acc = yl[wid * 64];
    int j = start;
    for (; j + 8 <= end; j += 8) {
        int s0 = csr_src[j + 0];
        int s1 = csr_src[j + 1];
        int s2 = csr_src[j + 2];
        int s3 = csr_src[j + 3];
        int s4 = csr_src[j + 4];
        int s5 = csr_src[j + 5];
        int s6 = csr_src[j + 6];
        int s7 = csr_src[j + 7];
        float v0 = yl[s0 * 64];
        float v1 = yl[s1 * 64];
        float v2 = yl[s2 * 64];
        float v3 = yl[s3 * 64];
        float v4 = yl[s4 * 64];
        float v5 = yl[s5 * 64];
        float v6 = yl[s6 * 64];
        float v7 = yl[s7 * 64];
        acc += ((v0 + v1) + (v2 + v3)) + ((v4 + v5) + (v6 + v7));
    }
    if (j + 4 <= end) {
        int s0 = csr_src[j + 0];
        int s1 = csr_src[j + 1];
        int s2 = csr_src[j + 2];
        int s3 = csr_src[j + 3];
        float v0 = yl[s0 * 64];
        float v1 = yl[s1 * 64];
        float v2 = yl[s2 * 64];
        float v3 = yl[s3 * 64];
        acc += (v0 + v1) + (v2 + v3);
        j += 4;
    }
    for (; j < end; j++) acc += yl[csr_src[j] * 64];
    u[wid * 64 + lane] = acc;
}

// ---------- gemm0: y0 = x @ W1_0 (N x 128 -> N x 64), register weights, 2 K-halves
__global__ __launch_bounds__(256) void gemm0_kernel(const float* __restrict__ x,
                                                    const float* __restrict__ W1,
                                                    float* __restrict__ y0,
                                                    int N, int totalWaves) {
    int lane = threadIdx.x & 63;
    int wid = (blockIdx.x * 256 + threadIdx.x) >> 6;
    float w[64];
#pragma unroll
    for (int k = 0; k < 64; k++) w[k] = W1[k * 64 + lane];
    for (int node = wid; node < N; node += totalWaves) {
        float xa = x[node * 128 + lane];
        float a0 = 0.f, a1 = 0.f, a2 = 0.f, a3 = 0.f;
#pragma unroll
        for (int k = 0; k < 64; k += 4) {
            a0 = fmaf(rl(xa, k + 0), w[k + 0], a0);
            a1 = fmaf(rl(xa, k + 1), w[k + 1], a1);
            a2 = fmaf(rl(xa, k + 2), w[k + 2], a2);
            a3 = fmaf(rl(xa, k + 3), w[k + 3], a3);
        }
        y0[node * 64 + lane] = (a0 + a1) + (a2 + a3);
    }
#pragma unroll
    for (int k = 0; k < 64; k++) w[k] = W1[(64 + k) * 64 + lane];
    for (int node = wid; node < N; node += totalWaves) {
        float xb = x[node * 128 + 64 + lane];
        float a0 = 0.f, a1 = 0.f, a2 = 0.f, a3 = 0.f;
#pragma unroll
        for (int k = 0; k < 64; k += 4) {
            a0 = fmaf(rl(xb, k + 0), w[k + 0], a0);
            a1 = fmaf(rl(xb, k + 1), w[k + 1], a1);
            a2 = fmaf(rl(xb, k + 2), w[k + 2], a2);
            a3 = fmaf(rl(xb, k + 3), w[k + 3], a3);
        }
        y0[node * 64 + lane] += (a0 + a1) + (a2 + a3);
    }
}

// ---------- mlpA: t = relu(u + b1); h = t @ W2 + b2 (relu if LAYER<2);
//            score (=/+)= h . Wm[LAYER]; store h (LAYER<2)
template <int LAYER>
__global__ __launch_bounds__(256) void mlpA_kernel(const float* __restrict__ u,
                                                   const float* __restrict__ b1,
                                                   const float* __restrict__ W2,
                                                   const float* __restrict__ b2,
                                                   const float* __restrict__ Wm,
                                                   float* __restrict__ hout,
                                                   float* __restrict__ score,
                                                   int N, int totalWaves) {
    int lane = threadIdx.x & 63;
    int wid = (blockIdx.x * 256 + threadIdx.x) >> 6;
    float w2[64];
#pragma unroll
    for (int k = 0; k < 64; k++) w2[k] = W2[k * 64 + lane];
    float bb1 = b1[lane], bb2 = b2[lane], wm = Wm[LAYER * 64 + lane];

    int node = wid;
    float uin = (node < N) ? u[node * 64 + lane] : 0.f;
    for (; node < N; node += totalWaves) {
        int nn = node + totalWaves;
        float unext = (nn < N) ? u[nn * 64 + lane] : 0.f;
        float t = fmaxf(uin + bb1, 0.f);
        float a0 = 0.f, a1 = 0.f, a2 = 0.f, a3 = 0.f;
#pragma unroll
        for (int k = 0; k < 64; k += 4) {
            a0 = fmaf(rl(t, k + 0), w2[k + 0], a0);
            a1 = fmaf(rl(t, k + 1), w2[k + 1], a1);
            a2 = fmaf(rl(t, k + 2), w2[k + 2], a2);
            a3 = fmaf(rl(t, k + 3), w2[k + 3], a3);
        }
        float h = bb2 + ((a0 + a1) + (a2 + a3));
        if (LAYER < 2) h = fmaxf(h, 0.f);
        float p = h * wm;
#pragma unroll
        for (int o = 32; o >= 1; o >>= 1) p += __shfl_xor(p, o);
        if (LAYER < 2) hout[node * 64 + lane] = h;
        if (lane == 0) {
            if (LAYER == 0) score[node] = p;
            else score[node] += p;
        }
        uin = unext;
    }
}

// ---------- mlpB: ynext = h @ W1next
__global__ __launch_bounds__(256) void mlpB_kernel(const float* __restrict__ h,
                                                   const float* __restrict__ W1n,
                                                   float* __restrict__ ynext,
                                                   int N, int totalWaves) {
    int lane = threadIdx.x & 63;
    int wid = (blockIdx.x * 256 + threadIdx.x) >> 6;
    float w[64];
#pragma unroll
    for (int k = 0; k < 64; k++) w[k] = W1n[k * 64 + lane];

    int node = wid;
    float hin = (node < N) ? h[node * 64 + lane] : 0.f;
    for (; node < N; node += totalWaves) {
        int nn = node + totalWaves;
        float hnext = (nn < N) ? h[nn * 64 + lane] : 0.f;
        float a0 = 0.f, a1 = 0.f, a2 = 0.f, a3 = 0.f;
#pragma unroll
        for (int k = 0; k < 64; k += 4) {
            a0 = fmaf(rl(hin, k + 0), w[k + 0], a0);
            a1 = fmaf(rl(hin, k + 1), w[k + 1], a1);
            a2 = fmaf(rl(hin, k + 2), w[k + 2], a2);
            a3 = fmaf(rl(hin, k + 3), w[k + 3], a3);
        }
        ynext[node * 64 + lane] = (a0 + a1) + (a2 + a3);
        hin = hnext;
    }
}

// ---------- edge softmax + new_score, per dst node ----------
__global__ __launch_bounds__(256) void edge_softmax_kernel(const float* __restrict__ score,
                                                           const int* __restrict__ rowptr,
                                                           const int* __restrict__ csr_src,
                                                           const float* __restrict__ bm,
                                                           float* __restrict__ nsf, int N) {
    int wid = (blockIdx.x * blockDim.x + threadIdx.x) >> 6;
    int lane = threadIdx.x & 63;
    if (wid >= N) return;
    float b = bm[0];
    float sd = score[wid] + b;
    int start = rowptr[wid];
    int end = rowptr[wid + 1];
    float m = -INFINITY;
    for (int j = start + lane; j < end; j += 64) {
        float ss = score[csr_src[j]] + b;
        m = fmaxf(m, ss * sd);
    }
#pragma unroll
    for (int o = 32; o >= 1; o >>= 1) m = fmaxf(m, __shfl_xor(m, o));
    float se = 0.f, swe = 0.f;
    if (m > -INFINITY) {
        for (int j = start + lane; j < end; j += 64) {
            float ss = score[csr_src[j]] + b;
            float e = expf(ss * sd - m);
            se += e;
            swe += ss * e;
        }
#pragma unroll
        for (int o = 32; o >= 1; o >>= 1) {
            se += __shfl_xor(se, o);
            swe += __shfl_xor(swe, o);
        }
    }
    float ns = (se > 0.f) ? (swe / se) : 0.f;
    if (lane == 0) nsf[wid] = sd + ns;
}

// ---------- graph-segment softmax ----------
__global__ void gmax_kernel(const float* __restrict__ nsf, const int* __restrict__ batch,
                            unsigned* __restrict__ gmaxu, int N) {
    int i = blockIdx.x * blockDim.x + threadIdx.x;
    if (i < N) atomicMax(&gmaxu[batch[i]], f2u_ord(nsf[i]));
}
__global__ void gexp_kernel(const float* __restrict__ nsf, const int* __restrict__ batch,
                            const unsigned* __restrict__ gmaxu, float* __restrict__ gsum,
                            float* __restrict__ out, int N) {
    int i = blockIdx.x * blockDim.x + threadIdx.x;
    if (i < N) {
        int b = batch[i];
        float m = u2f_ord(gmaxu[b]);
        float e = expf(nsf[i] - m);
        out[i] = e;
        atomicAdd(&gsum[b], e);
    }
}
__global__ void gdiv_kernel(const int* __restrict__ batch, const float* __restrict__ gsum,
                            float* __restrict__ out, int N) {
    int i = blockIdx.x * blockDim.x + threadIdx.x;
    if (i < N) out[i] /= gsum[batch[i]];
}

extern "C" void kernel_launch(void* const* d_in, const int* in_sizes, int n_in,
                              void* d_out, int out_size, void* d_ws, size_t ws_size,
                              hipStream_t stream) {
    const int N = N_NODES, E = N_EDGES, G = N_GRAPH;

    const float* x = (const float*)d_in[0];
    const int* ei = (const int*)d_in[1];
    const int* batch = (const int*)d_in[2];
    const float* W1a[3] = {(const float*)d_in[3], (const float*)d_in[7], (const float*)d_in[11]};
    const float* b1a[3] = {(const float*)d_in[4], (const float*)d_in[8], (const float*)d_in[12]};
    const float* W2a[3] = {(const float*)d_in[5], (const float*)d_in[9], (const float*)d_in[13]};
    const float* b2a[3] = {(const float*)d_in[6], (const float*)d_in[10], (const float*)d_in[14]};
    const float* Wm = (const float*)d_in[15];
    const float* bm = (const float*)d_in[16];
    float* out = (float*)d_out;

    const int* srcp = ei;
    const int* dstp = ei + E;

    // workspace layout
    float* yA = (float*)d_ws;                   // N*64
    float* yB = yA + (size_t)N * 64;            // N*64
    float* ubuf = yB + (size_t)N * 64;          // N*64
    float* hbuf = ubuf + (size_t)N * 64;        // N*64
    float* score = hbuf + (size_t)N * 64;       // N
    float* nsf = score + N;                     // N
    float* gsum = nsf + N;                      // G
    unsigned* gmaxu = (unsigned*)(gsum + G);    // G
    int* deg = (int*)(gmaxu + G);               // N
    int* rowptr = deg + N;                      // N+1
    int* cursor = rowptr + N + 1;               // N
    int* csr_src = cursor + N;                  // E

    hipMemsetAsync(deg, 0, sizeof(int) * N, stream);
    hipMemsetAsync(gmaxu, 0, sizeof(unsigned) * G, stream);
    hipMemsetAsync(gsum, 0, sizeof(float) * G, stream);

    hist_kernel<<<E / 256, 256, 0, stream>>>(dstp, deg, E);
    scan_kernel<<<1, 1024, 0, stream>>>(deg, rowptr, cursor, N);
    fill_kernel<<<E / 256, 256, 0, stream>>>(srcp, dstp, cursor, csr_src, E);

    const int gw = 4096;  // grid-stride waves for gemm/mlp kernels
    gemm0_kernel<<<1024, 256, 0, stream>>>(x, W1a[0], yA, N, gw);

    int aggBlocks = (N + 3) / 4;  // one wave per node

    // layer 0
    agg_kernel<<<aggBlocks, 256, 0, stream>>>(yA, rowptr, csr_src, ubuf, N);
    mlpA_kernel<0><<<1024, 256, 0, stream>>>(ubuf, b1a[0], W2a[0], b2a[0], Wm, hbuf, score, N, gw);
    mlpB_kernel<<<1024, 256, 0, stream>>>(hbuf, W1a[1], yB, N, gw);
    // layer 1
    agg_kernel<<<aggBlocks, 256, 0, stream>>>(yB, rowptr, csr_src, ubuf, N);
    mlpA_kernel<1><<<1024, 256, 0, stream>>>(ubuf, b1a[1], W2a[1], b2a[1], Wm, hbuf, score, N, gw);
    mlpB_kernel<<<1024, 256, 0, stream>>>(hbuf, W1a[2], yA, N, gw);
    // layer 2
    agg_kernel<<<aggBlocks, 256, 0, stream>>>(yA, rowptr, csr_src, ubuf, N);
    mlpA_kernel<2><<<1024, 256, 0, stream>>>(ubuf, b1a[2], W2a[2], b2a[2], Wm, nullptr, score, N, gw);

    edge_softmax_kernel<<<(N + 3) / 4, 256, 0, stream>>>(score, rowptr, csr_src, bm, nsf, N);

    int nb = (N + 255) / 256;
    gmax_kernel<<<nb, 256, 0, stream>>>(nsf, batch, gmaxu, N);
    gexp_kernel<<<nb, 256, 0, stream>>>(nsf, batch, gmaxu, gsum, out, N);
    gdiv_kernel<<<nb, 256, 0, stream>>>(batch, gsum, out, N);
}

// Round 4
// 504.751 us; speedup vs baseline: 3.3633x; 1.3314x over previous
//
#include <hip/hip_runtime.h>
#include <math.h>

#define N_NODES 50000
#define N_EDGES 1600000
#define N_GRAPH 500
#define NXCD 8

// ---------- helpers ----------
__device__ __forceinline__ unsigned f2u_ord(float f) {
    unsigned b = __float_as_uint(f);
    return (b & 0x80000000u) ? ~b : (b | 0x80000000u);
}
__device__ __forceinline__ float u2f_ord(unsigned u) {
    return __uint_as_float((u & 0x80000000u) ? (u ^ 0x80000000u) : ~u);
}
__device__ __forceinline__ float rl(float v, int k) {
    return __int_as_float(__builtin_amdgcn_readlane(__float_as_int(v), k));
}

// ---------- hist + per-edge rank ----------
__global__ void hist_kernel(const int* __restrict__ dst, int* __restrict__ deg,
                            int* __restrict__ rank, int E) {
    int e = blockIdx.x * blockDim.x + threadIdx.x;
    if (e < E) rank[e] = atomicAdd(&deg[dst[e]], 1);
}

// ---------- 3-phase scan ----------
__global__ __launch_bounds__(1024) void scan1_kernel(const int* __restrict__ deg,
                                                     int* __restrict__ part, int N) {
    int i = blockIdx.x * 1024 + threadIdx.x;
    int v = (i < N) ? deg[i] : 0;
#pragma unroll
    for (int o = 32; o >= 1; o >>= 1) v += __shfl_xor(v, o);
    __shared__ int red[16];
    if ((threadIdx.x & 63) == 0) red[threadIdx.x >> 6] = v;
    __syncthreads();
    if (threadIdx.x == 0) {
        int s = 0;
#pragma unroll
        for (int k = 0; k < 16; k++) s += red[k];
        part[blockIdx.x] = s;
    }
}

// single wave: exclusive scan of nb (<=64) partials; part[nb] = total
__global__ void scan2_kernel(int* __restrict__ part, int nb) {
    int lane = threadIdx.x;
    int v = (lane < nb) ? part[lane] : 0;
    int orig = v;
#pragma unroll
    for (int o = 1; o < 64; o <<= 1) {
        int t = __shfl_up(v, o);
        if (lane >= o) v += t;
    }
    if (lane < nb) part[lane] = v - orig;
    if (lane == nb - 1) part[nb] = v;
}

__global__ __launch_bounds__(1024) void scan3_kernel(const int* __restrict__ deg,
                                                     const int* __restrict__ part,
                                                     int* __restrict__ rowptr, int N) {
    int i = blockIdx.x * 1024 + threadIdx.x;
    int lane = threadIdx.x & 63;
    int w = threadIdx.x >> 6;
    int v = (i < N) ? deg[i] : 0;
    int inc = v;
#pragma unroll
    for (int o = 1; o < 64; o <<= 1) {
        int t = __shfl_up(inc, o);
        if (lane >= o) inc += t;
    }
    __shared__ int wsum[16];
    if (lane == 63) wsum[w] = inc;
    __syncthreads();
    if (threadIdx.x < 16) {
        int x = wsum[threadIdx.x];
        int xo = x;
#pragma unroll
        for (int o = 1; o < 16; o <<= 1) {
            int t = __shfl_up(x, o);
            if ((int)threadIdx.x >= o) x += t;
        }
        wsum[threadIdx.x] = x - xo;  // exclusive
    }
    __syncthreads();
    int base = part[blockIdx.x] + wsum[w];
    if (i < N) {
        rowptr[i] = base + inc - v;  // exclusive
        if (i == N - 1) rowptr[N] = base + inc;
    }
}

// ---------- fill: atomic-free, XCD-range-localized scatter ----------
__global__ __launch_bounds__(256) void fill_kernel(const int* __restrict__ src,
                                                   const int* __restrict__ dst,
                                                   const int* __restrict__ rank,
                                                   const int* __restrict__ rowptr,
                                                   int* __restrict__ csr_src,
                                                   int E, int nodesPerRange, int chunks) {
    int range = blockIdx.x & (NXCD - 1);
    int chunk = blockIdx.x >> 3;
    int lo = range * nodesPerRange;
    int hi = lo + nodesPerRange;
    int per = (E + chunks - 1) / chunks;
    int s = chunk * per;
    int e_end = min(s + per, E);
    for (int e = s + threadIdx.x; e < e_end; e += 256) {
        int d = dst[e];
        if (d >= lo && d < hi) {
            csr_src[rowptr[d] + rank[e]] = src[e];
        }
    }
}

// ---------- aggregation: u[d] = y[d] + sum y[src]; float4 lanes, 4 edge slots ----------
__global__ __launch_bounds__(256) void agg_kernel(const float* __restrict__ y,
                                                  const int* __restrict__ rowptr,
                                                  const int* __restrict__ csr_src,
                                                  float* __restrict__ u, int N) {
    int wid = (blockIdx.x * 256 + threadIdx.x) >> 6;
    int lane = threadIdx.x & 63;
    if (wid >= N) return;
    int q = lane >> 4;   // edge slot 0..3
    int r = lane & 15;   // feature quad 0..15
    int start = rowptr[wid];
    int end = rowptr[wid + 1];
    float4 acc = make_float4(0.f, 0.f, 0.f, 0.f);
    int j = start;
    for (; j + 16 <= end; j += 16) {
        int s0 = csr_src[j + q];
        int s1 = csr_src[j + 4 + q];
        int s2 = csr_src[j + 8 + q];
        int s3 = csr_src[j + 12 + q];
        float4 v0 = *(const float4*)(y + s0 * 64 + r * 4);
        float4 v1 = *(const float4*)(y + s1 * 64 + r * 4);
        float4 v2 = *(const float4*)(y + s2 * 64 + r * 4);
        float4 v3 = *(const float4*)(y + s3 * 64 + r * 4);
        acc.x += (v0.x + v1.x) + (v2.x + v3.x);
        acc.y += (v0.y + v1.y) + (v2.y + v3.y);
        acc.z += (v0.z + v1.z) + (v2.z + v3.z);
        acc.w += (v0.w + v1.w) + (v2.w + v3.w);
    }
    if (j + q < end) {  // predicated tail, up to 15 edges
#pragma unroll
        for (int m = 0; m < 4; m++) {
            int e = j + 4 * m + q;
            if (e < end) {
                int s = csr_src[e];
                float4 v = *(const float4*)(y + s * 64 + r * 4);
                acc.x += v.x; acc.y += v.y; acc.z += v.z; acc.w += v.w;
            }
        }
    }
    // combine edge slots (lanes l, l+16, l+32, l+48)
    acc.x += __shfl_xor(acc.x, 16);
    acc.y += __shfl_xor(acc.y, 16);
    acc.z += __shfl_xor(acc.z, 16);
    acc.w += __shfl_xor(acc.w, 16);
    acc.x += __shfl_xor(acc.x, 32);
    acc.y += __shfl_xor(acc.y, 32);
    acc.z += __shfl_xor(acc.z, 32);
    acc.w += __shfl_xor(acc.w, 32);
    if (lane < 16) {
        float4 self = *(const float4*)(y + wid * 64 + r * 4);
        acc.x += self.x; acc.y += self.y; acc.z += self.z; acc.w += self.w;
        *(float4*)(u + wid * 64 + r * 4) = acc;
    }
}

// ---------- gemm0: y0 = x @ W1_0 (N x 128 -> N x 64), register weights ----------
__global__ __launch_bounds__(256) void gemm0_kernel(const float* __restrict__ x,
                                                    const float* __restrict__ W1,
                                                    float* __restrict__ y0,
                                                    int N, int totalWaves) {
    int lane = threadIdx.x & 63;
    int wid = (blockIdx.x * 256 + threadIdx.x) >> 6;
    float w[64];
#pragma unroll
    for (int k = 0; k < 64; k++) w[k] = W1[k * 64 + lane];
    for (int node = wid; node < N; node += totalWaves) {
        float xa = x[node * 128 + lane];
        float a0 = 0.f, a1 = 0.f, a2 = 0.f, a3 = 0.f;
#pragma unroll
        for (int k = 0; k < 64; k += 4) {
            a0 = fmaf(rl(xa, k + 0), w[k + 0], a0);
            a1 = fmaf(rl(xa, k + 1), w[k + 1], a1);
            a2 = fmaf(rl(xa, k + 2), w[k + 2], a2);
            a3 = fmaf(rl(xa, k + 3), w[k + 3], a3);
        }
        y0[node * 64 + lane] = (a0 + a1) + (a2 + a3);
    }
#pragma unroll
    for (int k = 0; k < 64; k++) w[k] = W1[(64 + k) * 64 + lane];
    for (int node = wid; node < N; node += totalWaves) {
        float xb = x[node * 128 + 64 + lane];
        float a0 = 0.f, a1 = 0.f, a2 = 0.f, a3 = 0.f;
#pragma unroll
        for (int k = 0; k < 64; k += 4) {
            a0 = fmaf(rl(xb, k + 0), w[k + 0], a0);
            a1 = fmaf(rl(xb, k + 1), w[k + 1], a1);
            a2 = fmaf(rl(xb, k + 2), w[k + 2], a2);
            a3 = fmaf(rl(xb, k + 3), w[k + 3], a3);
        }
        y0[node * 64 + lane] += (a0 + a1) + (a2 + a3);
    }
}

// ---------- mlpA ----------
template <int LAYER>
__global__ __launch_bounds__(256) void mlpA_kernel(const float* __restrict__ u,
                                                   const float* __restrict__ b1,
                                                   const float* __restrict__ W2,
                                                   const float* __restrict__ b2,
                                                   const float* __restrict__ Wm,
                                                   float* __restrict__ hout,
                                                   float* __restrict__ score,
                                                   int N, int totalWaves) {
    int lane = threadIdx.x & 63;
    int wid = (blockIdx.x * 256 + threadIdx.x) >> 6;
    float w2[64];
#pragma unroll
    for (int k = 0; k < 64; k++) w2[k] = W2[k * 64 + lane];
    float bb1 = b1[lane], bb2 = b2[lane], wm = Wm[LAYER * 64 + lane];

    int node = wid;
    float uin = (node < N) ? u[node * 64 + lane] : 0.f;
    for (; node < N; node += totalWaves) {
        int nn = node + totalWaves;
        float unext = (nn < N) ? u[nn * 64 + lane] : 0.f;
        float t = fmaxf(uin + bb1, 0.f);
        float a0 = 0.f, a1 = 0.f, a2 = 0.f, a3 = 0.f;
#pragma unroll
        for (int k = 0; k < 64; k += 4) {
            a0 = fmaf(rl(t, k + 0), w2[k + 0], a0);
            a1 = fmaf(rl(t, k + 1), w2[k + 1], a1);
            a2 = fmaf(rl(t, k + 2), w2[k + 2], a2);
            a3 = fmaf(rl(t, k + 3), w2[k + 3], a3);
        }
        float h = bb2 + ((a0 + a1) + (a2 + a3));
        if (LAYER < 2) h = fmaxf(h, 0.f);
        float p = h * wm;
#pragma unroll
        for (int o = 32; o >= 1; o >>= 1) p += __shfl_xor(p, o);
        if (LAYER < 2) hout[node * 64 + lane] = h;
        if (lane == 0) {
            if (LAYER == 0) score[node] = p;
            else score[node] += p;
        }
        uin = unext;
    }
}

// ---------- mlpB ----------
__global__ __launch_bounds__(256) void mlpB_kernel(const float* __restrict__ h,
                                                   const float* __restrict__ W1n,
                                                   float* __restrict__ ynext,
                                                   int N, int totalWaves) {
    int lane = threadIdx.x & 63;
    int wid = (blockIdx.x * 256 + threadIdx.x) >> 6;
    float w[64];
#pragma unroll
    for (int k = 0; k < 64; k++) w[k] = W1n[k * 64 + lane];

    int node = wid;
    float hin = (node < N) ? h[node * 64 + lane] : 0.f;
    for (; node < N; node += totalWaves) {
        int nn = node + totalWaves;
        float hnext = (nn < N) ? h[nn * 64 + lane] : 0.f;
        float a0 = 0.f, a1 = 0.f, a2 = 0.f, a3 = 0.f;
#pragma unroll
        for (int k = 0; k < 64; k += 4) {
            a0 = fmaf(rl(hin, k + 0), w[k + 0], a0);
            a1 = fmaf(rl(hin, k + 1), w[k + 1], a1);
            a2 = fmaf(rl(hin, k + 2), w[k + 2], a2);
            a3 = fmaf(rl(hin, k + 3), w[k + 3], a3);
        }
        ynext[node * 64 + lane] = (a0 + a1) + (a2 + a3);
        hin = hnext;
    }
}

// ---------- edge softmax + new_score (single gather pass for deg<=64) ----------
__global__ __launch_bounds__(256) void edge_softmax_kernel(const float* __restrict__ score,
                                                           const int* __restrict__ rowptr,
                                                           const int* __restrict__ csr_src,
                                                           const float* __restrict__ bm,
                                                           float* __restrict__ nsf, int N) {
    int wid = (blockIdx.x * blockDim.x + threadIdx.x) >> 6;
    int lane = threadIdx.x & 63;
    if (wid >= N) return;
    float b = bm[0];
    float sd = score[wid] + b;
    int start = rowptr[wid];
    int end = rowptr[wid + 1];
    bool has0 = (start + lane < end);
    float ss0 = 0.f;
    float m = -INFINITY;
    if (has0) {
        ss0 = score[csr_src[start + lane]] + b;
        m = ss0 * sd;
    }
    for (int j = start + 64 + lane; j < end; j += 64) {
        float ss = score[csr_src[j]] + b;
        m = fmaxf(m, ss * sd);
    }
#pragma unroll
    for (int o = 32; o >= 1; o >>= 1) m = fmaxf(m, __shfl_xor(m, o));
    float se = 0.f, swe = 0.f;
    if (m > -INFINITY) {
        if (has0) {
            float e0 = expf(ss0 * sd - m);
            se += e0;
            swe += ss0 * e0;
        }
        for (int j = start + 64 + lane; j < end; j += 64) {
            float ss = score[csr_src[j]] + b;
            float e = expf(ss * sd - m);
            se += e;
            swe += ss * e;
        }
#pragma unroll
        for (int o = 32; o >= 1; o >>= 1) {
            se += __shfl_xor(se, o);
            swe += __shfl_xor(swe, o);
        }
    }
    float ns = (se > 0.f) ? (swe / se) : 0.f;
    if (lane == 0) nsf[wid] = sd + ns;
}

// ---------- graph-segment softmax ----------
__global__ void gmax_kernel(const float* __restrict__ nsf, const int* __restrict__ batch,
                            unsigned* __restrict__ gmaxu, int N) {
    int i = blockIdx.x * blockDim.x + threadIdx.x;
    if (i < N) atomicMax(&gmaxu[batch[i]], f2u_ord(nsf[i]));
}
__global__ void gexp_kernel(const float* __restrict__ nsf, const int* __restrict__ batch,
                            const unsigned* __restrict__ gmaxu, float* __restrict__ gsum,
                            float* __restrict__ out, int N) {
    int i = blockIdx.x * blockDim.x + threadIdx.x;
    if (i < N) {
        int b = batch[i];
        float m = u2f_ord(gmaxu[b]);
        float e = expf(nsf[i] - m);
        out[i] = e;
        atomicAdd(&gsum[b], e);
    }
}
__global__ void gdiv_kernel(const int* __restrict__ batch, const float* __restrict__ gsum,
                            float* __restrict__ out, int N) {
    int i = blockIdx.x * blockDim.x + threadIdx.x;
    if (i < N) out[i] /= gsum[batch[i]];
}

extern "C" void kernel_launch(void* const* d_in, const int* in_sizes, int n_in,
                              void* d_out, int out_size, void* d_ws, size_t ws_size,
                              hipStream_t stream) {
    const int N = N_NODES, E = N_EDGES, G = N_GRAPH;

    const float* x = (const float*)d_in[0];
    const int* ei = (const int*)d_in[1];
    const int* batch = (const int*)d_in[2];
    const float* W1a[3] = {(const float*)d_in[3], (const float*)d_in[7], (const float*)d_in[11]};
    const float* b1a[3] = {(const float*)d_in[4], (const float*)d_in[8], (const float*)d_in[12]};
    const float* W2a[3] = {(const float*)d_in[5], (const float*)d_in[9], (const float*)d_in[13]};
    const float* b2a[3] = {(const float*)d_in[6], (const float*)d_in[10], (const float*)d_in[14]};
    const float* Wm = (const float*)d_in[15];
    const float* bm = (const float*)d_in[16];
    float* out = (float*)d_out;

    const int* srcp = ei;
    const int* dstp = ei + E;

    // workspace layout
    float* yA = (float*)d_ws;                   // N*64
    float* yB = yA + (size_t)N * 64;            // N*64
    float* ubuf = yB + (size_t)N * 64;          // N*64
    float* hbuf = ubuf + (size_t)N * 64;        // N*64
    float* score = hbuf + (size_t)N * 64;       // N
    float* nsf = score + N;                     // N
    float* gsum = nsf + N;                      // G
    unsigned* gmaxu = (unsigned*)(gsum + G);    // G
    int* deg = (int*)(gmaxu + G);               // N
    int* rowptr = deg + N;                      // N+1
    int* part = rowptr + N + 1;                 // 64
    int* rank = part + 64;                      // E
    int* csr_src = rank + E;                    // E

    hipMemsetAsync(deg, 0, sizeof(int) * N, stream);
    hipMemsetAsync(gmaxu, 0, sizeof(unsigned) * G, stream);
    hipMemsetAsync(gsum, 0, sizeof(float) * G, stream);

    hist_kernel<<<E / 256, 256, 0, stream>>>(dstp, deg, rank, E);

    const int nbScan = (N + 1023) / 1024;  // 49
    scan1_kernel<<<nbScan, 1024, 0, stream>>>(deg, part, N);
    scan2_kernel<<<1, 64, 0, stream>>>(part, nbScan);
    scan3_kernel<<<nbScan, 1024, 0, stream>>>(deg, part, rowptr, N);

    const int chunks = 64;
    fill_kernel<<<chunks * NXCD, 256, 0, stream>>>(srcp, dstp, rank, rowptr, csr_src,
                                                   E, N / NXCD, chunks);

    const int gw = 4096;
    gemm0_kernel<<<1024, 256, 0, stream>>>(x, W1a[0], yA, N, gw);

    int aggBlocks = (N + 3) / 4;

    agg_kernel<<<aggBlocks, 256, 0, stream>>>(yA, rowptr, csr_src, ubuf, N);
    mlpA_kernel<0><<<1024, 256, 0, stream>>>(ubuf, b1a[0], W2a[0], b2a[0], Wm, hbuf, score, N, gw);
    mlpB_kernel<<<1024, 256, 0, stream>>>(hbuf, W1a[1], yB, N, gw);

    agg_kernel<<<aggBlocks, 256, 0, stream>>>(yB, rowptr, csr_src, ubuf, N);
    mlpA_kernel<1><<<1024, 256, 0, stream>>>(ubuf, b1a[1], W2a[1], b2a[1], Wm, hbuf, score, N, gw);
    mlpB_kernel<<<1024, 256, 0, stream>>>(hbuf, W1a[2], yA, N, gw);

    agg_kernel<<<aggBlocks, 256, 0, stream>>>(yA, rowptr, csr_src, ubuf, N);
    mlpA_kernel<2><<<1024, 256, 0, stream>>>(ubuf, b1a[2], W2a[2], b2a[2], Wm, nullptr, score, N, gw);

    edge_softmax_kernel<<<(N + 3) / 4, 256, 0, stream>>>(score, rowptr, csr_src, bm, nsf, N);

    int nb = (N + 255) / 256;
    gmax_kernel<<<nb, 256, 0, stream>>>(nsf, batch, gmaxu, N);
    gexp_kernel<<<nb, 256, 0, stream>>>(nsf, batch, gmaxu, gsum, out, N);
    gdiv_kernel<<<nb, 256, 0, stream>>>(batch, gsum, out, N);
}